// Round 1
// 461.148 us; speedup vs baseline: 1.1980x; 1.1980x over previous
//
#include <hip/hip_runtime.h>
#include <hip/hip_bf16.h>

typedef unsigned short u16;
typedef unsigned int   u32;

typedef __attribute__((ext_vector_type(8))) short short8;
typedef __attribute__((ext_vector_type(4))) float floatx4;

#define HD __device__ __forceinline__

HD float bf16_lo(u32 u) { union { u32 i; float f; } v; v.i = u << 16; return v.f; }
HD float bf16_hi(u32 u) { union { u32 i; float f; } v; v.i = u & 0xffff0000u; return v.f; }
HD u16 f2bf(float f) {
    __hip_bfloat16 h = __float2bfloat16(f);
    u16 s; __builtin_memcpy(&s, &h, 2); return s;
}

// CSR bucketing parameters: 256 nodes per bucket (bucket = dst >> 8)
#define NPB   256
#define MAXNB 512          // supports N <= 131072
#define CH    4096         // edges per coarse chunk

// ---- dtype detect: flag=1 if x is packed bf16, 0 if fp32 ----
__global__ void k_detect(const u32* __restrict__ xw, int* __restrict__ flag) {
    __shared__ int cnt;
    if (threadIdx.x == 0) cnt = 0;
    __syncthreads();
    int sane = 0;
    for (int i = threadIdx.x; i < 4096; i += 256) {
        u32 v = xw[i];
        int e = (v >> 7) & 0xFF;
        sane += (e >= 107 && e <= 147) ? 1 : 0;
    }
    atomicAdd(&cnt, sane);
    __syncthreads();
    if (threadIdx.x == 0) *flag = (cnt > 2048) ? 1 : 0;
}

// ---- bucket histogram: LDS per-block then one global atomic per bucket ----
__global__ void k_bhist(const int* __restrict__ dst, int* __restrict__ gbcnt, int E) {
    __shared__ int h[MAXNB];
    for (int i = threadIdx.x; i < MAXNB; i += 256) h[i] = 0;
    __syncthreads();
    int base = blockIdx.x * CH;
    int end  = min(base + CH, E);
    for (int i = base + threadIdx.x; i < end; i += 256)
        atomicAdd(&h[dst[i] >> 8], 1);
    __syncthreads();
    for (int i = threadIdx.x; i < MAXNB; i += 256)
        if (h[i]) atomicAdd(&gbcnt[i], h[i]);
}

// ---- single-wave exclusive scan of bucket counts -> gboff, gbcursor ----
__global__ void k_bscan(const int* __restrict__ gbcnt, int* __restrict__ gboff,
                        int* __restrict__ gbcursor, int NB) {
    int lane = threadIdx.x;
    int carry = 0;
    int T = (NB + 63) / 64;
    for (int t = 0; t < T; t++) {
        int i = t * 64 + lane;
        int v = (i < NB) ? gbcnt[i] : 0;
        int x = v;
#pragma unroll
        for (int off = 1; off < 64; off <<= 1) {
            int y = __shfl_up(x, off);
            if (lane >= off) x += y;
        }
        if (i < NB) { int ex = carry + x - v; gboff[i] = ex; gbcursor[i] = ex; }
        carry += __shfl(x, 63);
    }
    if (lane == 0) gboff[NB] = carry;
}

// ---- coarse scatter: chunk -> LDS reorder by bucket -> contiguous run copy ----
// Writes (src,dst) pairs grouped by bucket. Each bucket's pairs segment is
// [gboff[b], gboff[b+1]). Write runs avg ~10 pairs (~84B) -> mostly-full lines.
__global__ void __launch_bounds__(256)
k_coarse(const int* __restrict__ ei, int* __restrict__ gbcursor,
         int2* __restrict__ pairs, int E) {
    __shared__ int  hist[MAXNB];
    __shared__ int  gs[MAXNB];
    __shared__ int  dlt[MAXNB];
    __shared__ int  lofs[MAXNB];
    __shared__ int2 lp[CH];
    __shared__ u16  pb[CH];
    const int* srcp = ei;
    const int* dstp = ei + E;
    int base = blockIdx.x * CH;
    int cnt  = min(CH, E - base);

    for (int i = threadIdx.x; i < MAXNB; i += 256) hist[i] = 0;
    __syncthreads();

    int2 e[16];
    int nb_ = 0;
#pragma unroll
    for (int j = 0; j < 16; j++) {
        int i = base + threadIdx.x + j * 256;
        if (i < E) {
            e[j].x = srcp[i];
            e[j].y = dstp[i];
            atomicAdd(&hist[e[j].y >> 8], 1);
            nb_ = j + 1;
        }
    }
    __syncthreads();

    // wave0: exclusive scan of hist into gs
    if (threadIdx.x < 64) {
        int lane = threadIdx.x;
        int carry = 0;
#pragma unroll
        for (int t = 0; t < MAXNB / 64; t++) {
            int i = t * 64 + lane;
            int v = hist[i];
            int x = v;
#pragma unroll
            for (int off = 1; off < 64; off <<= 1) {
                int y = __shfl_up(x, off);
                if (lane >= off) x += y;
            }
            gs[i] = carry + x - v;
            carry += __shfl(x, 63);
        }
    }
    __syncthreads();

    // reserve global space per bucket (one atomic per non-empty bucket)
    for (int b = threadIdx.x; b < MAXNB; b += 256) {
        int c = hist[b];
        lofs[b] = gs[b];
        if (c > 0) {
            int gbase = atomicAdd(&gbcursor[b], c);
            dlt[b] = gbase - gs[b];
        }
    }
    __syncthreads();

    // scatter into LDS grouped by bucket
    for (int j = 0; j < nb_; j++) {
        int b = e[j].y >> 8;
        int p = atomicAdd(&lofs[b], 1);
        lp[p] = e[j];
        pb[p] = (u16)b;
    }
    __syncthreads();

    // contiguous-run copy to global
    for (int p = threadIdx.x; p < cnt; p += 256) {
        pairs[p + dlt[pb[p]]] = lp[p];
    }
}

// ---- per-node counts from bucketed pairs (LDS atomics only) ----
__global__ void k_nodecnt(const int2* __restrict__ pairs, const int* __restrict__ gboff,
                          int* __restrict__ cnt, int N) {
    __shared__ int lc[NPB];
    int b = blockIdx.x;
    int nbase = b * NPB;
    lc[threadIdx.x] = 0;
    __syncthreads();
    int p0 = gboff[b], p1 = gboff[b + 1];
    for (int p = p0 + threadIdx.x; p < p1; p += 256)
        atomicAdd(&lc[pairs[p].y - nbase], 1);
    __syncthreads();
    int node = nbase + threadIdx.x;
    if (node < N) cnt[node] = lc[threadIdx.x];
}

// ---- fine scatter: one block per bucket, cursors in LDS, writes L2-local ----
__global__ void k_fine(const int2* __restrict__ pairs, const int* __restrict__ gboff,
                       const int* __restrict__ rowptr, int* __restrict__ col, int N) {
    __shared__ int lcur[NPB];
    int b = blockIdx.x;
    int nbase = b * NPB;
    int node = nbase + threadIdx.x;
    lcur[threadIdx.x] = (node < N) ? rowptr[node] : 0;
    __syncthreads();
    int p0 = gboff[b], p1 = gboff[b + 1];
    for (int p = p0 + threadIdx.x; p < p1; p += 256) {
        int2 e = pairs[p];
        int pos = atomicAdd(&lcur[e.y - nbase], 1);
        col[pos] = e.x;
    }
}

// ---- dinv[i] = rsqrt(cnt[i] + 1) ----
__global__ void k_dinv(const int* __restrict__ cnt, float* __restrict__ dinv, int N) {
    int i = blockIdx.x * blockDim.x + threadIdx.x;
    if (i < N) dinv[i] = rsqrtf((float)cnt[i] + 1.0f);
}

// ---- hierarchical scan: (1) per-1024-block sums ----
__global__ void k_blocksum(const int* __restrict__ cnt, int* __restrict__ partial, int N) {
    __shared__ int wsum[4];
    int base = blockIdx.x * 1024;
    int s = 0;
#pragma unroll
    for (int j = 0; j < 4; j++) {
        int i = base + j * 256 + threadIdx.x;
        if (i < N) s += cnt[i];
    }
#pragma unroll
    for (int off = 32; off > 0; off >>= 1) s += __shfl_down(s, off);
    if ((threadIdx.x & 63) == 0) wsum[threadIdx.x >> 6] = s;
    __syncthreads();
    if (threadIdx.x == 0) partial[blockIdx.x] = wsum[0] + wsum[1] + wsum[2] + wsum[3];
}

// ---- (2) single-wave exclusive scan of P partials; writes rowptr[N]=E ----
__global__ void k_scanpart(int* __restrict__ partial, int* __restrict__ rowptrN, int P) {
    int lane = threadIdx.x;
    int carry = 0;
    int T = (P + 63) / 64;
    for (int t = 0; t < T; t++) {
        int i = t * 64 + lane;
        int v = (i < P) ? partial[i] : 0;
        int x = v;
#pragma unroll
        for (int off = 1; off < 64; off <<= 1) {
            int y = __shfl_up(x, off);
            if (lane >= off) x += y;
        }
        if (i < P) partial[i] = carry + x - v;     // exclusive
        carry += __shfl(x, 63);
    }
    if (lane == 0) *rowptrN = carry;
}

// ---- (3) per-block scan + add partial offset -> rowptr ----
__global__ void __launch_bounds__(1024)
k_scanfinal(const int* __restrict__ cnt, const int* __restrict__ partial,
            int* __restrict__ rowptr, int* __restrict__ cursor, int N) {
    __shared__ int ws[16];
    int lane = threadIdx.x & 63, wid = threadIdx.x >> 6;
    int i = blockIdx.x * 1024 + threadIdx.x;
    int v = (i < N) ? cnt[i] : 0;
    int x = v;
#pragma unroll
    for (int off = 1; off < 64; off <<= 1) {
        int y = __shfl_up(x, off);
        if (lane >= off) x += y;
    }
    if (lane == 63) ws[wid] = x;
    __syncthreads();
    if (wid == 0) {
        int w = (lane < 16) ? ws[lane] : 0;
        int wx = w;
#pragma unroll
        for (int off = 1; off < 16; off <<= 1) {
            int y = __shfl_up(wx, off);
            if (lane >= off) wx += y;
        }
        if (lane < 16) ws[lane] = wx - w;
    }
    __syncthreads();
    int excl = partial[blockIdx.x] + ws[wid] + (x - v);
    if (i < N) { rowptr[i] = excl; cursor[i] = excl; }
}

// ---- transpose both 128x128 weights -> bf16 Wt[c][k] = W[k][c] ----
__global__ void k_transpose(const void* __restrict__ W1, const void* __restrict__ W2,
                            u16* __restrict__ W1t, u16* __restrict__ W2t,
                            const int* __restrict__ flagp) {
    int isbf = *flagp;
    int i = blockIdx.x * blockDim.x + threadIdx.x;   // 0 .. 32767
    int w = i >> 14;
    int r = (i >> 7) & 127;
    int c = i & 127;
    const void* W = w ? W2 : W1;
    u16*       Wt = w ? W2t : W1t;
    u16 val;
    if (isbf) val = ((const u16*)W)[c * 128 + r];
    else      val = f2bf(((const float*)W)[c * 128 + r]);
    Wt[r * 128 + c] = val;
}

// ---- GEMM: out[r][c] = sum_k in[r][k] * W[k][c], K=C=128, bf16 out ----
template <int MODE>
__global__ void k_gemm(const void* __restrict__ inp, const u16* __restrict__ Wt,
                       u16* __restrict__ outb, int ntiles, const int* __restrict__ flagp) {
    __shared__ u16 stage[4][16 * 136];
    int isbf = (MODE == 0) ? *flagp : 1;
    int gw   = (blockIdx.x * blockDim.x + threadIdx.x) >> 6;
    int nw   = (gridDim.x * blockDim.x) >> 6;
    int lane = threadIdx.x & 63;
    int wid  = threadIdx.x >> 6;
    int m = lane & 15, q = lane >> 4;
    u16* st = stage[wid];

    for (int t = gw; t < ntiles; t += nw) {
        long r0 = (long)t * 16;
        floatx4 acc[8];
#pragma unroll
        for (int nt = 0; nt < 8; nt++) acc[nt] = (floatx4)0.0f;

#pragma unroll
        for (int kk = 0; kk < 4; kk++) {
            int k0 = kk * 32 + q * 8;
            short8 a;
            if (MODE == 1) {
                const float4* fp = (const float4*)((const float*)inp + (r0 + m) * 128 + k0);
                float4 f0 = fp[0], f1 = fp[1];
                a[0] = (short)f2bf(fmaxf(f0.x, 0.0f)); a[1] = (short)f2bf(fmaxf(f0.y, 0.0f));
                a[2] = (short)f2bf(fmaxf(f0.z, 0.0f)); a[3] = (short)f2bf(fmaxf(f0.w, 0.0f));
                a[4] = (short)f2bf(fmaxf(f1.x, 0.0f)); a[5] = (short)f2bf(fmaxf(f1.y, 0.0f));
                a[6] = (short)f2bf(fmaxf(f1.z, 0.0f)); a[7] = (short)f2bf(fmaxf(f1.w, 0.0f));
            } else if (isbf) {
                a = *(const short8*)((const u16*)inp + (r0 + m) * 128 + k0);
            } else {
                const float4* fp = (const float4*)((const float*)inp + (r0 + m) * 128 + k0);
                float4 f0 = fp[0], f1 = fp[1];
                a[0] = (short)f2bf(f0.x); a[1] = (short)f2bf(f0.y);
                a[2] = (short)f2bf(f0.z); a[3] = (short)f2bf(f0.w);
                a[4] = (short)f2bf(f1.x); a[5] = (short)f2bf(f1.y);
                a[6] = (short)f2bf(f1.z); a[7] = (short)f2bf(f1.w);
            }
#pragma unroll
            for (int nt = 0; nt < 8; nt++) {
                short8 b = *(const short8*)(Wt + (nt * 16 + m) * 128 + k0);
                acc[nt] = __builtin_amdgcn_mfma_f32_16x16x32_bf16(a, b, acc[nt], 0, 0, 0);
            }
        }
#pragma unroll
        for (int nt = 0; nt < 8; nt++) {
#pragma unroll
            for (int i = 0; i < 4; i++) {
                st[(q * 4 + i) * 136 + nt * 16 + m] = f2bf(acc[nt][i]);
            }
        }
        __builtin_amdgcn_s_waitcnt(0);   // lgkm drain (same-wave LDS RAW)
        u16* gbase = outb + (size_t)r0 * 128;
#pragma unroll
        for (int j = 0; j < 4; j++) {
            int e   = lane * 8 + j * 512;
            int row = e >> 7, colu = e & 127;
            short8 vv = *(const short8*)&st[row * 136 + colu];
            *(short8*)(gbase + e) = vv;
        }
    }
}

// ---- CSR aggregation: one wave per node ----
template <int FINAL>
__global__ void k_csr_agg(const u16* __restrict__ Hb, const int* __restrict__ col,
                          const int* __restrict__ rowptr, const float* __restrict__ dinv,
                          void* __restrict__ outp, int N, const int* __restrict__ flagp) {
    int isbf = FINAL ? *flagp : 0;
    int gw   = (blockIdx.x * blockDim.x + threadIdx.x) >> 6;
    int nw   = (gridDim.x * blockDim.x) >> 6;
    int lane = threadIdx.x & 63;
    for (int n = gw; n < N; n += nw) {
        int r0 = rowptr[n], r1 = rowptr[n + 1];
        float di = dinv[n];
        u32 h = *(const u32*)(Hb + (size_t)n * 128 + lane * 2);
        float c = di * di;
        float a0 = bf16_lo(h) * c, a1 = bf16_hi(h) * c;
        int e = r0;
        for (; e + 3 < r1; e += 4) {
            int s0 = col[e], s1 = col[e + 1], s2 = col[e + 2], s3 = col[e + 3];
            float c0 = dinv[s0] * di, c1 = dinv[s1] * di;
            float c2 = dinv[s2] * di, c3 = dinv[s3] * di;
            u32 h0 = *(const u32*)(Hb + (size_t)s0 * 128 + lane * 2);
            u32 h1 = *(const u32*)(Hb + (size_t)s1 * 128 + lane * 2);
            u32 h2 = *(const u32*)(Hb + (size_t)s2 * 128 + lane * 2);
            u32 h3 = *(const u32*)(Hb + (size_t)s3 * 128 + lane * 2);
            a0 += bf16_lo(h0) * c0; a1 += bf16_hi(h0) * c0;
            a0 += bf16_lo(h1) * c1; a1 += bf16_hi(h1) * c1;
            a0 += bf16_lo(h2) * c2; a1 += bf16_hi(h2) * c2;
            a0 += bf16_lo(h3) * c3; a1 += bf16_hi(h3) * c3;
        }
        for (; e < r1; e++) {
            int s = col[e];
            float cf = dinv[s] * di;
            u32 hh = *(const u32*)(Hb + (size_t)s * 128 + lane * 2);
            a0 += bf16_lo(hh) * cf; a1 += bf16_hi(hh) * cf;
        }
        if (FINAL && isbf) {
            ((u32*)outp)[(size_t)n * 64 + lane] = (u32)f2bf(a0) | ((u32)f2bf(a1) << 16);
        } else {
            ((float2*)outp)[(size_t)n * 64 + lane] = make_float2(a0, a1);
        }
    }
}

extern "C" void kernel_launch(void* const* d_in, const int* in_sizes, int n_in,
                              void* d_out, int out_size, void* d_ws, size_t ws_size,
                              hipStream_t stream) {
    const void* x  = d_in[0];
    const int*  ei = (const int*)d_in[1];
    const void* W1 = d_in[2];
    const void* W2 = d_in[3];

    const int N = in_sizes[0] / 128;   // 100000
    const int E = in_sizes[1] / 2;     // 1600000

    char* ws = (char*)d_ws;
    float* dinv    = (float*)ws;                         // 400KB
    int*   cnt     = (int*)(ws + (512u << 10));          // 400KB
    int*   rowptr  = (int*)(ws + (1024u << 10));         // 400KB+4
    int*   partial = (int*)(ws + (1536u << 10));         // ~512B
    int*   gbcnt   = (int*)(ws + (1600u << 10));         // (MAXNB+1)*4
    int*   gboff   = (int*)(ws + (1664u << 10));         // (MAXNB+1)*4
    int*   gbcur   = (int*)(ws + (1728u << 10));         // (MAXNB+1)*4
    int*   flag    = (int*)(ws + (1984u << 10));         // 4B
    u16*   W1t     = (u16*)(ws + (2048u << 10));         // 32KB
    u16*   W2t     = W1t + 128 * 128;                    // 32KB
    int*   col     = (int*)(ws + (3u << 20));            // E*4 = 6.4MB
    u16*   Hb      = (u16*)(ws + (10u << 20));           // N*256B = 25.6MB
    float* A       = (float*)(ws + (40u << 20));         // N*512B = 51.2MB
    int2*  pairs   = (int2*)(ws + (40u << 20));          // 12.8MB, aliases A (dead then)

    int P   = (N + 1023) / 1024;        // 98 scan blocks
    int NB  = (N + NPB - 1) / NPB;      // 391 buckets
    int nch = (E + CH - 1) / CH;        // 391 coarse chunks

    // ---- graph preprocessing (CSR by dst, bucketed build) ----
    k_detect<<<1, 256, 0, stream>>>((const u32*)x, flag);
    hipMemsetAsync(gbcnt, 0, (size_t)(MAXNB + 1) * 4, stream);
    k_bhist<<<nch, 256, 0, stream>>>(ei + E, gbcnt, E);
    k_bscan<<<1, 64, 0, stream>>>(gbcnt, gboff, gbcur, NB);
    k_coarse<<<nch, 256, 0, stream>>>(ei, gbcur, pairs, E);
    k_nodecnt<<<NB, 256, 0, stream>>>(pairs, gboff, cnt, N);
    k_dinv<<<(N + 255) / 256, 256, 0, stream>>>(cnt, dinv, N);
    k_blocksum<<<P, 256, 0, stream>>>(cnt, partial, N);
    k_scanpart<<<1, 64, 0, stream>>>(partial, rowptr + N, P);
    k_scanfinal<<<P, 1024, 0, stream>>>(cnt, partial, rowptr, cnt /*cursor*/, N);
    k_fine<<<NB, 256, 0, stream>>>(pairs, gboff, rowptr, col, N);
    k_transpose<<<128, 256, 0, stream>>>(W1, W2, W1t, W2t, flag);

    int ntiles  = N / 16;                 // 6250
    int gblocks = (ntiles + 3) / 4;
    int ablocks = (N + 3) / 4;            // one wave per node

    // layer 1
    k_gemm<0><<<gblocks, 256, 0, stream>>>(x, W1t, Hb, ntiles, flag);
    k_csr_agg<0><<<ablocks, 256, 0, stream>>>(Hb, col, rowptr, dinv, A, N, flag);

    // layer 2 (relu fused into GEMM input read; output fused into agg)
    k_gemm<1><<<gblocks, 256, 0, stream>>>(A, W2t, Hb, ntiles, flag);
    k_csr_agg<1><<<ablocks, 256, 0, stream>>>(Hb, col, rowptr, dinv, d_out, N, flag);
}

// Round 2
// 429.264 us; speedup vs baseline: 1.2869x; 1.0743x over previous
//
#include <hip/hip_runtime.h>
#include <hip/hip_bf16.h>

typedef unsigned short u16;
typedef unsigned int   u32;

typedef __attribute__((ext_vector_type(8))) short short8;
typedef __attribute__((ext_vector_type(4))) float floatx4;

#define HD __device__ __forceinline__

HD float bf16_lo(u32 u) { union { u32 i; float f; } v; v.i = u << 16; return v.f; }
HD float bf16_hi(u32 u) { union { u32 i; float f; } v; v.i = u & 0xffff0000u; return v.f; }
HD u16 f2bf(float f) {
    __hip_bfloat16 h = __float2bfloat16(f);
    u16 s; __builtin_memcpy(&s, &h, 2); return s;
}

// CSR bucketing parameters: 256 nodes per bucket (bucket = dst >> 8)
#define NPB   256
#define MAXNB 512          // supports N <= 131072
#define CH    4096         // edges per coarse chunk

// ---- dtype detect: flag=1 if x is packed bf16, 0 if fp32 ----
__global__ void k_detect(const u32* __restrict__ xw, int* __restrict__ flag) {
    __shared__ int cnt;
    if (threadIdx.x == 0) cnt = 0;
    __syncthreads();
    int sane = 0;
    for (int i = threadIdx.x; i < 4096; i += 256) {
        u32 v = xw[i];
        int e = (v >> 7) & 0xFF;
        sane += (e >= 107 && e <= 147) ? 1 : 0;
    }
    atomicAdd(&cnt, sane);
    __syncthreads();
    if (threadIdx.x == 0) *flag = (cnt > 2048) ? 1 : 0;
}

// ---- bucket histogram: LDS per-block then one global atomic per bucket ----
__global__ void k_bhist(const int* __restrict__ dst, int* __restrict__ gbcnt, int E) {
    __shared__ int h[MAXNB];
    for (int i = threadIdx.x; i < MAXNB; i += 256) h[i] = 0;
    __syncthreads();
    int base = blockIdx.x * CH;
    int end  = min(base + CH, E);
    for (int i = base + threadIdx.x; i < end; i += 256)
        atomicAdd(&h[dst[i] >> 8], 1);
    __syncthreads();
    for (int i = threadIdx.x; i < MAXNB; i += 256)
        if (h[i]) atomicAdd(&gbcnt[i], h[i]);
}

// ---- single-wave exclusive scan of bucket counts -> gboff, gbcursor ----
__global__ void k_bscan(const int* __restrict__ gbcnt, int* __restrict__ gboff,
                        int* __restrict__ gbcursor, int NB) {
    int lane = threadIdx.x;
    int carry = 0;
    int T = (NB + 63) / 64;
    for (int t = 0; t < T; t++) {
        int i = t * 64 + lane;
        int v = (i < NB) ? gbcnt[i] : 0;
        int x = v;
#pragma unroll
        for (int off = 1; off < 64; off <<= 1) {
            int y = __shfl_up(x, off);
            if (lane >= off) x += y;
        }
        if (i < NB) { int ex = carry + x - v; gboff[i] = ex; gbcursor[i] = ex; }
        carry += __shfl(x, 63);
    }
    if (lane == 0) gboff[NB] = carry;
}

// ---- coarse scatter: chunk -> LDS reorder by bucket -> contiguous run copy ----
__global__ void __launch_bounds__(256)
k_coarse(const int* __restrict__ ei, int* __restrict__ gbcursor,
         int2* __restrict__ pairs, int E) {
    __shared__ int  hist[MAXNB];
    __shared__ int  gs[MAXNB];
    __shared__ int  dlt[MAXNB];
    __shared__ int  lofs[MAXNB];
    __shared__ int2 lp[CH];
    __shared__ u16  pb[CH];
    const int* srcp = ei;
    const int* dstp = ei + E;
    int base = blockIdx.x * CH;
    int cnt  = min(CH, E - base);

    for (int i = threadIdx.x; i < MAXNB; i += 256) hist[i] = 0;
    __syncthreads();

    int2 e[16];
    int nb_ = 0;
#pragma unroll
    for (int j = 0; j < 16; j++) {
        int i = base + threadIdx.x + j * 256;
        if (i < E) {
            e[j].x = srcp[i];
            e[j].y = dstp[i];
            atomicAdd(&hist[e[j].y >> 8], 1);
            nb_ = j + 1;
        }
    }
    __syncthreads();

    // wave0: exclusive scan of hist into gs
    if (threadIdx.x < 64) {
        int lane = threadIdx.x;
        int carry = 0;
#pragma unroll
        for (int t = 0; t < MAXNB / 64; t++) {
            int i = t * 64 + lane;
            int v = hist[i];
            int x = v;
#pragma unroll
            for (int off = 1; off < 64; off <<= 1) {
                int y = __shfl_up(x, off);
                if (lane >= off) x += y;
            }
            gs[i] = carry + x - v;
            carry += __shfl(x, 63);
        }
    }
    __syncthreads();

    // reserve global space per bucket (one atomic per non-empty bucket)
    for (int b = threadIdx.x; b < MAXNB; b += 256) {
        int c = hist[b];
        lofs[b] = gs[b];
        if (c > 0) {
            int gbase = atomicAdd(&gbcursor[b], c);
            dlt[b] = gbase - gs[b];
        }
    }
    __syncthreads();

    // scatter into LDS grouped by bucket
    for (int j = 0; j < nb_; j++) {
        int b = e[j].y >> 8;
        int p = atomicAdd(&lofs[b], 1);
        lp[p] = e[j];
        pb[p] = (u16)b;
    }
    __syncthreads();

    // contiguous-run copy to global
    for (int p = threadIdx.x; p < cnt; p += 256) {
        pairs[p + dlt[pb[p]]] = lp[p];
    }
}

// ---- per-node counts from bucketed pairs (LDS atomics only) ----
__global__ void k_nodecnt(const int2* __restrict__ pairs, const int* __restrict__ gboff,
                          int* __restrict__ cnt, int N) {
    __shared__ int lc[NPB];
    int b = blockIdx.x;
    int nbase = b * NPB;
    lc[threadIdx.x] = 0;
    __syncthreads();
    int p0 = gboff[b], p1 = gboff[b + 1];
    for (int p = p0 + threadIdx.x; p < p1; p += 256)
        atomicAdd(&lc[pairs[p].y - nbase], 1);
    __syncthreads();
    int node = nbase + threadIdx.x;
    if (node < N) cnt[node] = lc[threadIdx.x];
}

// ---- fine scatter: one block per bucket, cursors in LDS, writes L2-local ----
__global__ void k_fine(const int2* __restrict__ pairs, const int* __restrict__ gboff,
                       const int* __restrict__ rowptr, int* __restrict__ col, int N) {
    __shared__ int lcur[NPB];
    int b = blockIdx.x;
    int nbase = b * NPB;
    int node = nbase + threadIdx.x;
    lcur[threadIdx.x] = (node < N) ? rowptr[node] : 0;
    __syncthreads();
    int p0 = gboff[b], p1 = gboff[b + 1];
    for (int p = p0 + threadIdx.x; p < p1; p += 256) {
        int2 e = pairs[p];
        int pos = atomicAdd(&lcur[e.y - nbase], 1);
        col[pos] = e.x;
    }
}

// ---- dinv[i] = rsqrt(cnt[i] + 1) ----
__global__ void k_dinv(const int* __restrict__ cnt, float* __restrict__ dinv, int N) {
    int i = blockIdx.x * blockDim.x + threadIdx.x;
    if (i < N) dinv[i] = rsqrtf((float)cnt[i] + 1.0f);
}

// ---- hierarchical scan: (1) per-1024-block sums ----
__global__ void k_blocksum(const int* __restrict__ cnt, int* __restrict__ partial, int N) {
    __shared__ int wsum[4];
    int base = blockIdx.x * 1024;
    int s = 0;
#pragma unroll
    for (int j = 0; j < 4; j++) {
        int i = base + j * 256 + threadIdx.x;
        if (i < N) s += cnt[i];
    }
#pragma unroll
    for (int off = 32; off > 0; off >>= 1) s += __shfl_down(s, off);
    if ((threadIdx.x & 63) == 0) wsum[threadIdx.x >> 6] = s;
    __syncthreads();
    if (threadIdx.x == 0) partial[blockIdx.x] = wsum[0] + wsum[1] + wsum[2] + wsum[3];
}

// ---- (2) single-wave exclusive scan of P partials; writes rowptr[N]=E ----
__global__ void k_scanpart(int* __restrict__ partial, int* __restrict__ rowptrN, int P) {
    int lane = threadIdx.x;
    int carry = 0;
    int T = (P + 63) / 64;
    for (int t = 0; t < T; t++) {
        int i = t * 64 + lane;
        int v = (i < P) ? partial[i] : 0;
        int x = v;
#pragma unroll
        for (int off = 1; off < 64; off <<= 1) {
            int y = __shfl_up(x, off);
            if (lane >= off) x += y;
        }
        if (i < P) partial[i] = carry + x - v;     // exclusive
        carry += __shfl(x, 63);
    }
    if (lane == 0) *rowptrN = carry;
}

// ---- (3) per-block scan + add partial offset -> rowptr ----
__global__ void __launch_bounds__(1024)
k_scanfinal(const int* __restrict__ cnt, const int* __restrict__ partial,
            int* __restrict__ rowptr, int* __restrict__ cursor, int N) {
    __shared__ int ws[16];
    int lane = threadIdx.x & 63, wid = threadIdx.x >> 6;
    int i = blockIdx.x * 1024 + threadIdx.x;
    int v = (i < N) ? cnt[i] : 0;
    int x = v;
#pragma unroll
    for (int off = 1; off < 64; off <<= 1) {
        int y = __shfl_up(x, off);
        if (lane >= off) x += y;
    }
    if (lane == 63) ws[wid] = x;
    __syncthreads();
    if (wid == 0) {
        int w = (lane < 16) ? ws[lane] : 0;
        int wx = w;
#pragma unroll
        for (int off = 1; off < 16; off <<= 1) {
            int y = __shfl_up(wx, off);
            if (lane >= off) wx += y;
        }
        if (lane < 16) ws[lane] = wx - w;
    }
    __syncthreads();
    int excl = partial[blockIdx.x] + ws[wid] + (x - v);
    if (i < N) { rowptr[i] = excl; cursor[i] = excl; }
}

// ---- transpose both 128x128 weights -> bf16 Wt[c][k] = W[k][c] ----
__global__ void k_transpose(const void* __restrict__ W1, const void* __restrict__ W2,
                            u16* __restrict__ W1t, u16* __restrict__ W2t,
                            const int* __restrict__ flagp) {
    int isbf = *flagp;
    int i = blockIdx.x * blockDim.x + threadIdx.x;   // 0 .. 32767
    int w = i >> 14;
    int r = (i >> 7) & 127;
    int c = i & 127;
    const void* W = w ? W2 : W1;
    u16*       Wt = w ? W2t : W1t;
    u16 val;
    if (isbf) val = ((const u16*)W)[c * 128 + r];
    else      val = f2bf(((const float*)W)[c * 128 + r]);
    Wt[r * 128 + c] = val;
}

// ---- GEMM: out[r][c] = sum_k in[r][k] * W[k][c], K=C=128, bf16 out ----
// MODE 0: input x (dtype per flag). MODE 1: input bf16 (A, relu pre-applied).
template <int MODE>
__global__ void k_gemm(const void* __restrict__ inp, const u16* __restrict__ Wt,
                       u16* __restrict__ outb, int ntiles, const int* __restrict__ flagp) {
    __shared__ u16 stage[4][16 * 136];
    int isbf = (MODE == 0) ? *flagp : 1;
    int gw   = (blockIdx.x * blockDim.x + threadIdx.x) >> 6;
    int nw   = (gridDim.x * blockDim.x) >> 6;
    int lane = threadIdx.x & 63;
    int wid  = threadIdx.x >> 6;
    int m = lane & 15, q = lane >> 4;
    u16* st = stage[wid];

    for (int t = gw; t < ntiles; t += nw) {
        long r0 = (long)t * 16;
        floatx4 acc[8];
#pragma unroll
        for (int nt = 0; nt < 8; nt++) acc[nt] = (floatx4)0.0f;

#pragma unroll
        for (int kk = 0; kk < 4; kk++) {
            int k0 = kk * 32 + q * 8;
            short8 a;
            if (MODE == 1 || isbf) {
                a = *(const short8*)((const u16*)inp + (r0 + m) * 128 + k0);
            } else {
                const float4* fp = (const float4*)((const float*)inp + (r0 + m) * 128 + k0);
                float4 f0 = fp[0], f1 = fp[1];
                a[0] = (short)f2bf(f0.x); a[1] = (short)f2bf(f0.y);
                a[2] = (short)f2bf(f0.z); a[3] = (short)f2bf(f0.w);
                a[4] = (short)f2bf(f1.x); a[5] = (short)f2bf(f1.y);
                a[6] = (short)f2bf(f1.z); a[7] = (short)f2bf(f1.w);
            }
#pragma unroll
            for (int nt = 0; nt < 8; nt++) {
                short8 b = *(const short8*)(Wt + (nt * 16 + m) * 128 + k0);
                acc[nt] = __builtin_amdgcn_mfma_f32_16x16x32_bf16(a, b, acc[nt], 0, 0, 0);
            }
        }
#pragma unroll
        for (int nt = 0; nt < 8; nt++) {
#pragma unroll
            for (int i = 0; i < 4; i++) {
                st[(q * 4 + i) * 136 + nt * 16 + m] = f2bf(acc[nt][i]);
            }
        }
        __builtin_amdgcn_s_waitcnt(0);   // lgkm drain (same-wave LDS RAW)
        u16* gbase = outb + (size_t)r0 * 128;
#pragma unroll
        for (int j = 0; j < 4; j++) {
            int e   = lane * 8 + j * 512;
            int row = e >> 7, colu = e & 127;
            short8 vv = *(const short8*)&st[row * 136 + colu];
            *(short8*)(gbase + e) = vv;
        }
    }
}

// ---- CSR aggregation: one wave per node, batched-gather pipeline ----
// Per 64-edge chunk: cooperative col load (1 coalesced read) + parallel dinv
// gather, then all Hb row-gathers are independent (addresses from shuffles)
// -> 8 row fetches in flight per wave instead of a col->dinv->Hb serial chain.
// MODE 0: write bf16 with fused relu (intermediate A).
// MODE 1: final output (bf16 or fp32 per flag).
template <int MODE>
__global__ void k_csr_agg(const u16* __restrict__ Hb, const int* __restrict__ col,
                          const int* __restrict__ rowptr, const float* __restrict__ dinv,
                          void* __restrict__ outp, int N, const int* __restrict__ flagp) {
    int isbf = MODE ? *flagp : 1;
    int gw   = (blockIdx.x * blockDim.x + threadIdx.x) >> 6;
    int nw   = (gridDim.x * blockDim.x) >> 6;
    int lane = threadIdx.x & 63;
    for (int n = gw; n < N; n += nw) {
        int r0 = rowptr[n], r1 = rowptr[n + 1];
        float di = dinv[n];
        u32 h = *(const u32*)(Hb + (size_t)n * 128 + lane * 2);
        float c = di * di;
        float a0 = bf16_lo(h) * c, a1 = bf16_hi(h) * c;

        for (int base = r0; base < r1; base += 64) {
            int cnt = min(64, r1 - base);
            int   myc = (lane < cnt) ? col[base + lane] : 0;
            float mdv = (lane < cnt) ? dinv[myc] : 0.0f;
            int e = 0;
            for (; e + 7 < cnt; e += 8) {
                u32 hh[8]; float cf[8];
#pragma unroll
                for (int j = 0; j < 8; j++) {
                    int   s = __shfl(myc, e + j);
                    cf[j]   = __shfl(mdv, e + j) * di;
                    hh[j]   = *(const u32*)(Hb + (size_t)s * 128 + lane * 2);
                }
#pragma unroll
                for (int j = 0; j < 8; j++) {
                    a0 += bf16_lo(hh[j]) * cf[j];
                    a1 += bf16_hi(hh[j]) * cf[j];
                }
            }
            for (; e + 3 < cnt; e += 4) {
                u32 hh[4]; float cf[4];
#pragma unroll
                for (int j = 0; j < 4; j++) {
                    int   s = __shfl(myc, e + j);
                    cf[j]   = __shfl(mdv, e + j) * di;
                    hh[j]   = *(const u32*)(Hb + (size_t)s * 128 + lane * 2);
                }
#pragma unroll
                for (int j = 0; j < 4; j++) {
                    a0 += bf16_lo(hh[j]) * cf[j];
                    a1 += bf16_hi(hh[j]) * cf[j];
                }
            }
            for (; e < cnt; e++) {
                int   s  = __shfl(myc, e);
                float cf = __shfl(mdv, e) * di;
                u32  hh  = *(const u32*)(Hb + (size_t)s * 128 + lane * 2);
                a0 += bf16_lo(hh) * cf; a1 += bf16_hi(hh) * cf;
            }
        }

        if (MODE == 0) {
            // intermediate: fused relu + bf16 pack (bit-identical to
            // fp32-store-then-f2bf(fmax) done by the old gemm input path)
            float r0f = fmaxf(a0, 0.0f), r1f = fmaxf(a1, 0.0f);
            ((u32*)outp)[(size_t)n * 64 + lane] = (u32)f2bf(r0f) | ((u32)f2bf(r1f) << 16);
        } else if (isbf) {
            ((u32*)outp)[(size_t)n * 64 + lane] = (u32)f2bf(a0) | ((u32)f2bf(a1) << 16);
        } else {
            ((float2*)outp)[(size_t)n * 64 + lane] = make_float2(a0, a1);
        }
    }
}

extern "C" void kernel_launch(void* const* d_in, const int* in_sizes, int n_in,
                              void* d_out, int out_size, void* d_ws, size_t ws_size,
                              hipStream_t stream) {
    const void* x  = d_in[0];
    const int*  ei = (const int*)d_in[1];
    const void* W1 = d_in[2];
    const void* W2 = d_in[3];

    const int N = in_sizes[0] / 128;   // 100000
    const int E = in_sizes[1] / 2;     // 1600000

    char* ws = (char*)d_ws;
    float* dinv    = (float*)ws;                         // 400KB
    int*   cnt     = (int*)(ws + (512u << 10));          // 400KB
    int*   rowptr  = (int*)(ws + (1024u << 10));         // 400KB+4
    int*   partial = (int*)(ws + (1536u << 10));         // ~512B
    int*   gbcnt   = (int*)(ws + (1600u << 10));         // (MAXNB+1)*4
    int*   gboff   = (int*)(ws + (1664u << 10));         // (MAXNB+1)*4
    int*   gbcur   = (int*)(ws + (1728u << 10));         // (MAXNB+1)*4
    int*   flag    = (int*)(ws + (1984u << 10));         // 4B
    u16*   W1t     = (u16*)(ws + (2048u << 10));         // 32KB
    u16*   W2t     = W1t + 128 * 128;                    // 32KB
    int*   col     = (int*)(ws + (3u << 20));            // E*4 = 6.4MB
    u16*   Hb      = (u16*)(ws + (10u << 20));           // N*256B = 25.6MB
    u16*   A       = (u16*)(ws + (40u << 20));           // N*256B = 25.6MB (bf16, relu'd)
    int2*  pairs   = (int2*)(ws + (70u << 20));          // 12.8MB (dead after k_fine)

    int P   = (N + 1023) / 1024;        // 98 scan blocks
    int NB  = (N + NPB - 1) / NPB;      // 391 buckets
    int nch = (E + CH - 1) / CH;        // 391 coarse chunks

    // ---- graph preprocessing (CSR by dst, bucketed build) ----
    k_detect<<<1, 256, 0, stream>>>((const u32*)x, flag);
    hipMemsetAsync(gbcnt, 0, (size_t)(MAXNB + 1) * 4, stream);
    k_bhist<<<nch, 256, 0, stream>>>(ei + E, gbcnt, E);
    k_bscan<<<1, 64, 0, stream>>>(gbcnt, gboff, gbcur, NB);
    k_coarse<<<nch, 256, 0, stream>>>(ei, gbcur, pairs, E);
    k_nodecnt<<<NB, 256, 0, stream>>>(pairs, gboff, cnt, N);
    k_dinv<<<(N + 255) / 256, 256, 0, stream>>>(cnt, dinv, N);
    k_blocksum<<<P, 256, 0, stream>>>(cnt, partial, N);
    k_scanpart<<<1, 64, 0, stream>>>(partial, rowptr + N, P);
    k_scanfinal<<<P, 1024, 0, stream>>>(cnt, partial, rowptr, cnt /*cursor*/, N);
    k_fine<<<NB, 256, 0, stream>>>(pairs, gboff, rowptr, col, N);
    k_transpose<<<128, 256, 0, stream>>>(W1, W2, W1t, W2t, flag);

    int ntiles  = N / 16;                 // 6250
    int gblocks = (ntiles + 3) / 4;
    int ablocks = (N + 3) / 4;            // one wave per node

    // layer 1
    k_gemm<0><<<gblocks, 256, 0, stream>>>(x, W1t, Hb, ntiles, flag);
    k_csr_agg<0><<<ablocks, 256, 0, stream>>>(Hb, col, rowptr, dinv, A, N, flag);

    // layer 2 (relu fused into agg1 output; final dtype fused into agg2)
    k_gemm<1><<<gblocks, 256, 0, stream>>>(A, W2t, Hb, ntiles, flag);
    k_csr_agg<1><<<ablocks, 256, 0, stream>>>(Hb, col, rowptr, dinv, d_out, N, flag);
}

// Round 3
// 344.557 us; speedup vs baseline: 1.6033x; 1.2458x over previous
//
#include <hip/hip_runtime.h>
#include <hip/hip_bf16.h>

typedef unsigned short u16;
typedef unsigned int   u32;

typedef __attribute__((ext_vector_type(8))) short short8;
typedef __attribute__((ext_vector_type(4))) float floatx4;

#define HD __device__ __forceinline__

HD float bf16_lo(u32 u) { union { u32 i; float f; } v; v.i = u << 16; return v.f; }
HD float bf16_hi(u32 u) { union { u32 i; float f; } v; v.i = u & 0xffff0000u; return v.f; }
HD u16 f2bf(float f) {
    __hip_bfloat16 h = __float2bfloat16(f);
    u16 s; __builtin_memcpy(&s, &h, 2); return s;
}

// CSR bucketing parameters: 256 nodes per bucket (bucket = dst >> 8)
#define NPB   256
#define MAXNB 512          // supports N <= 131072
#define CH    4096         // edges per coarse chunk

// ---- dtype detect: flag=1 if x is packed bf16, 0 if fp32 ----
__global__ void k_detect(const u32* __restrict__ xw, int* __restrict__ flag) {
    __shared__ int cnt;
    if (threadIdx.x == 0) cnt = 0;
    __syncthreads();
    int sane = 0;
    for (int i = threadIdx.x; i < 4096; i += 256) {
        u32 v = xw[i];
        int e = (v >> 7) & 0xFF;
        sane += (e >= 107 && e <= 147) ? 1 : 0;
    }
    atomicAdd(&cnt, sane);
    __syncthreads();
    if (threadIdx.x == 0) *flag = (cnt > 2048) ? 1 : 0;
}

// ---- bucket histogram: LDS per-block then one global atomic per bucket ----
__global__ void k_bhist(const int* __restrict__ dst, int* __restrict__ gbcnt, int E) {
    __shared__ int h[MAXNB];
    for (int i = threadIdx.x; i < MAXNB; i += 256) h[i] = 0;
    __syncthreads();
    int base = blockIdx.x * CH;
    int end  = min(base + CH, E);
    for (int i = base + threadIdx.x; i < end; i += 256)
        atomicAdd(&h[dst[i] >> 8], 1);
    __syncthreads();
    for (int i = threadIdx.x; i < MAXNB; i += 256)
        if (h[i]) atomicAdd(&gbcnt[i], h[i]);
}

// ---- single-wave exclusive scan of bucket counts -> gboff, gbcursor ----
__global__ void k_bscan(const int* __restrict__ gbcnt, int* __restrict__ gboff,
                        int* __restrict__ gbcursor, int NB) {
    int lane = threadIdx.x;
    int carry = 0;
    int T = (NB + 63) / 64;
    for (int t = 0; t < T; t++) {
        int i = t * 64 + lane;
        int v = (i < NB) ? gbcnt[i] : 0;
        int x = v;
#pragma unroll
        for (int off = 1; off < 64; off <<= 1) {
            int y = __shfl_up(x, off);
            if (lane >= off) x += y;
        }
        if (i < NB) { int ex = carry + x - v; gboff[i] = ex; gbcursor[i] = ex; }
        carry += __shfl(x, 63);
    }
    if (lane == 0) gboff[NB] = carry;
}

// ---- coarse scatter: chunk -> LDS reorder by bucket -> contiguous run copy ----
__global__ void __launch_bounds__(256)
k_coarse(const int* __restrict__ ei, int* __restrict__ gbcursor,
         int2* __restrict__ pairs, int E) {
    __shared__ int  hist[MAXNB];
    __shared__ int  gs[MAXNB];
    __shared__ int  dlt[MAXNB];
    __shared__ int  lofs[MAXNB];
    __shared__ int2 lp[CH];
    __shared__ u16  pb[CH];
    const int* srcp = ei;
    const int* dstp = ei + E;
    int base = blockIdx.x * CH;
    int cnt  = min(CH, E - base);

    for (int i = threadIdx.x; i < MAXNB; i += 256) hist[i] = 0;
    __syncthreads();

    int2 e[16];
    int nb_ = 0;
#pragma unroll
    for (int j = 0; j < 16; j++) {
        int i = base + threadIdx.x + j * 256;
        if (i < E) {
            e[j].x = srcp[i];
            e[j].y = dstp[i];
            atomicAdd(&hist[e[j].y >> 8], 1);
            nb_ = j + 1;
        }
    }
    __syncthreads();

    // wave0: exclusive scan of hist into gs
    if (threadIdx.x < 64) {
        int lane = threadIdx.x;
        int carry = 0;
#pragma unroll
        for (int t = 0; t < MAXNB / 64; t++) {
            int i = t * 64 + lane;
            int v = hist[i];
            int x = v;
#pragma unroll
            for (int off = 1; off < 64; off <<= 1) {
                int y = __shfl_up(x, off);
                if (lane >= off) x += y;
            }
            gs[i] = carry + x - v;
            carry += __shfl(x, 63);
        }
    }
    __syncthreads();

    // reserve global space per bucket (one atomic per non-empty bucket)
    for (int b = threadIdx.x; b < MAXNB; b += 256) {
        int c = hist[b];
        lofs[b] = gs[b];
        if (c > 0) {
            int gbase = atomicAdd(&gbcursor[b], c);
            dlt[b] = gbase - gs[b];
        }
    }
    __syncthreads();

    // scatter into LDS grouped by bucket
    for (int j = 0; j < nb_; j++) {
        int b = e[j].y >> 8;
        int p = atomicAdd(&lofs[b], 1);
        lp[p] = e[j];
        pb[p] = (u16)b;
    }
    __syncthreads();

    // contiguous-run copy to global
    for (int p = threadIdx.x; p < cnt; p += 256) {
        pairs[p + dlt[pb[p]]] = lp[p];
    }
}

// ---- per-node counts from bucketed pairs (LDS atomics only) ----
__global__ void k_nodecnt(const int2* __restrict__ pairs, const int* __restrict__ gboff,
                          int* __restrict__ cnt, int N) {
    __shared__ int lc[NPB];
    int b = blockIdx.x;
    int nbase = b * NPB;
    lc[threadIdx.x] = 0;
    __syncthreads();
    int p0 = gboff[b], p1 = gboff[b + 1];
    for (int p = p0 + threadIdx.x; p < p1; p += 256)
        atomicAdd(&lc[pairs[p].y - nbase], 1);
    __syncthreads();
    int node = nbase + threadIdx.x;
    if (node < N) cnt[node] = lc[threadIdx.x];
}

// ---- fine scatter: one block per bucket, cursors in LDS, writes L2-local ----
__global__ void k_fine(const int2* __restrict__ pairs, const int* __restrict__ gboff,
                       const int* __restrict__ rowptr, int* __restrict__ col, int N) {
    __shared__ int lcur[NPB];
    int b = blockIdx.x;
    int nbase = b * NPB;
    int node = nbase + threadIdx.x;
    lcur[threadIdx.x] = (node < N) ? rowptr[node] : 0;
    __syncthreads();
    int p0 = gboff[b], p1 = gboff[b + 1];
    for (int p = p0 + threadIdx.x; p < p1; p += 256) {
        int2 e = pairs[p];
        int pos = atomicAdd(&lcur[e.y - nbase], 1);
        col[pos] = e.x;
    }
}

// ---- dinv[i] = rsqrt(cnt[i] + 1) ----
__global__ void k_dinv(const int* __restrict__ cnt, float* __restrict__ dinv, int N) {
    int i = blockIdx.x * blockDim.x + threadIdx.x;
    if (i < N) dinv[i] = rsqrtf((float)cnt[i] + 1.0f);
}

// ---- hierarchical scan: (1) per-1024-block sums ----
__global__ void k_blocksum(const int* __restrict__ cnt, int* __restrict__ partial, int N) {
    __shared__ int wsum[4];
    int base = blockIdx.x * 1024;
    int s = 0;
#pragma unroll
    for (int j = 0; j < 4; j++) {
        int i = base + j * 256 + threadIdx.x;
        if (i < N) s += cnt[i];
    }
#pragma unroll
    for (int off = 32; off > 0; off >>= 1) s += __shfl_down(s, off);
    if ((threadIdx.x & 63) == 0) wsum[threadIdx.x >> 6] = s;
    __syncthreads();
    if (threadIdx.x == 0) partial[blockIdx.x] = wsum[0] + wsum[1] + wsum[2] + wsum[3];
}

// ---- (2) single-wave exclusive scan of P partials; writes rowptr[N]=E ----
__global__ void k_scanpart(int* __restrict__ partial, int* __restrict__ rowptrN, int P) {
    int lane = threadIdx.x;
    int carry = 0;
    int T = (P + 63) / 64;
    for (int t = 0; t < T; t++) {
        int i = t * 64 + lane;
        int v = (i < P) ? partial[i] : 0;
        int x = v;
#pragma unroll
        for (int off = 1; off < 64; off <<= 1) {
            int y = __shfl_up(x, off);
            if (lane >= off) x += y;
        }
        if (i < P) partial[i] = carry + x - v;     // exclusive
        carry += __shfl(x, 63);
    }
    if (lane == 0) *rowptrN = carry;
}

// ---- (3) per-block scan + add partial offset -> rowptr ----
__global__ void __launch_bounds__(1024)
k_scanfinal(const int* __restrict__ cnt, const int* __restrict__ partial,
            int* __restrict__ rowptr, int* __restrict__ cursor, int N) {
    __shared__ int ws[16];
    int lane = threadIdx.x & 63, wid = threadIdx.x >> 6;
    int i = blockIdx.x * 1024 + threadIdx.x;
    int v = (i < N) ? cnt[i] : 0;
    int x = v;
#pragma unroll
    for (int off = 1; off < 64; off <<= 1) {
        int y = __shfl_up(x, off);
        if (lane >= off) x += y;
    }
    if (lane == 63) ws[wid] = x;
    __syncthreads();
    if (wid == 0) {
        int w = (lane < 16) ? ws[lane] : 0;
        int wx = w;
#pragma unroll
        for (int off = 1; off < 16; off <<= 1) {
            int y = __shfl_up(wx, off);
            if (lane >= off) wx += y;
        }
        if (lane < 16) ws[lane] = wx - w;
    }
    __syncthreads();
    int excl = partial[blockIdx.x] + ws[wid] + (x - v);
    if (i < N) { rowptr[i] = excl; cursor[i] = excl; }
}

// ---- transpose both 128x128 weights -> bf16 Wt[c][k] = W[k][c] ----
__global__ void k_transpose(const void* __restrict__ W1, const void* __restrict__ W2,
                            u16* __restrict__ W1t, u16* __restrict__ W2t,
                            const int* __restrict__ flagp) {
    int isbf = *flagp;
    int i = blockIdx.x * blockDim.x + threadIdx.x;   // 0 .. 32767
    int w = i >> 14;
    int r = (i >> 7) & 127;
    int c = i & 127;
    const void* W = w ? W2 : W1;
    u16*       Wt = w ? W2t : W1t;
    u16 val;
    if (isbf) val = ((const u16*)W)[c * 128 + r];
    else      val = f2bf(((const float*)W)[c * 128 + r]);
    Wt[r * 128 + c] = val;
}

// ---- GEMM: out[r][c] = sum_k in[r][k] * W[k][c], K=C=128, bf16 out ----
// Weights staged to LDS once per block (XOR-swizzled 16B slots: slot ^= row&7
// -> conflict-free ds_read_b128 B-fragments). Each wave computes a 32x128
// tile (2 row-groups sharing each B frag): per K-step 8 ds_read + 16 MFMA.
// All 8 A-loads per wave issued up front (independent, in flight together).
// MODE 0: input x (dtype per flag). MODE 1: input bf16 (A, relu pre-applied).
template <int MODE>
__global__ void __launch_bounds__(256)
k_gemm(const void* __restrict__ inp, const u16* __restrict__ Wt,
       u16* __restrict__ outb, int ntiles, const int* __restrict__ flagp) {
    __shared__ u16 lw[128 * 128];        // weights [c][k], swizzled slots
    __shared__ u16 stage[4][16 * 136];   // per-wave C staging
    int isbf = (MODE == 0) ? *flagp : 1;
    int gw   = (blockIdx.x * blockDim.x + threadIdx.x) >> 6;
    int nw   = (gridDim.x * blockDim.x) >> 6;
    int lane = threadIdx.x & 63;
    int wid  = threadIdx.x >> 6;
    int m = lane & 15, q = lane >> 4;
    u16* st = stage[wid];

    // stage weights: 256 threads, each covers half a row (8 x 16B slots)
    {
        int r = threadIdx.x >> 1;
        int h = threadIdx.x & 1;
        const short8* src = (const short8*)(Wt + r * 128 + h * 64);
#pragma unroll
        for (int jj = 0; jj < 8; jj++) {
            int slot = h * 8 + jj;
            *(short8*)&lw[r * 128 + ((slot ^ (r & 7)) << 3)] = src[jj];
        }
    }
    __syncthreads();

    for (int t = gw; t < ntiles; t += nw) {
        long r0 = (long)t * 32;
        floatx4 acc[2][8];
#pragma unroll
        for (int g = 0; g < 2; g++)
#pragma unroll
            for (int nt = 0; nt < 8; nt++) acc[g][nt] = (floatx4)0.0f;

        // hoisted A loads: 8 independent 16B fetches
        short8 a[2][4];
        if (MODE == 1 || isbf) {
#pragma unroll
            for (int g = 0; g < 2; g++)
#pragma unroll
                for (int kk = 0; kk < 4; kk++)
                    a[g][kk] = *(const short8*)((const u16*)inp +
                                 (r0 + g * 16 + m) * 128 + kk * 32 + q * 8);
        } else {
#pragma unroll
            for (int g = 0; g < 2; g++)
#pragma unroll
                for (int kk = 0; kk < 4; kk++) {
                    const float4* fp = (const float4*)((const float*)inp +
                                 (r0 + g * 16 + m) * 128 + kk * 32 + q * 8);
                    float4 f0 = fp[0], f1 = fp[1];
                    short8 v;
                    v[0] = (short)f2bf(f0.x); v[1] = (short)f2bf(f0.y);
                    v[2] = (short)f2bf(f0.z); v[3] = (short)f2bf(f0.w);
                    v[4] = (short)f2bf(f1.x); v[5] = (short)f2bf(f1.y);
                    v[6] = (short)f2bf(f1.z); v[7] = (short)f2bf(f1.w);
                    a[g][kk] = v;
                }
        }

#pragma unroll
        for (int kk = 0; kk < 4; kk++) {
#pragma unroll
            for (int nt = 0; nt < 8; nt++) {
                int slot = kk * 4 + q;
                short8 b = *(const short8*)&lw[(nt * 16 + m) * 128 +
                                               ((slot ^ (m & 7)) << 3)];
                acc[0][nt] = __builtin_amdgcn_mfma_f32_16x16x32_bf16(a[0][kk], b, acc[0][nt], 0, 0, 0);
                acc[1][nt] = __builtin_amdgcn_mfma_f32_16x16x32_bf16(a[1][kk], b, acc[1][nt], 0, 0, 0);
            }
        }

        // epilogue: stage each 16x128 row-group in LDS, coalesced store
#pragma unroll
        for (int g = 0; g < 2; g++) {
#pragma unroll
            for (int nt = 0; nt < 8; nt++)
#pragma unroll
                for (int i = 0; i < 4; i++)
                    st[(q * 4 + i) * 136 + nt * 16 + m] = f2bf(acc[g][nt][i]);
            __builtin_amdgcn_s_waitcnt(0);   // drain ds_write before read
            u16* gbase = outb + (size_t)(r0 + g * 16) * 128;
#pragma unroll
            for (int j = 0; j < 4; j++) {
                int e   = lane * 8 + j * 512;
                int row = e >> 7, colu = e & 127;
                short8 vv = *(const short8*)&st[row * 136 + colu];
                *(short8*)(gbase + e) = vv;
            }
            __builtin_amdgcn_s_waitcnt(0);   // reads done before g=1 rewrites
        }
    }
}

// ---- CSR aggregation: one wave per node, batched-gather pipeline ----
// MODE 0: write bf16 with fused relu (intermediate A).
// MODE 1: final output (bf16 or fp32 per flag).
template <int MODE>
__global__ void k_csr_agg(const u16* __restrict__ Hb, const int* __restrict__ col,
                          const int* __restrict__ rowptr, const float* __restrict__ dinv,
                          void* __restrict__ outp, int N, const int* __restrict__ flagp) {
    int isbf = MODE ? *flagp : 1;
    int gw   = (blockIdx.x * blockDim.x + threadIdx.x) >> 6;
    int nw   = (gridDim.x * blockDim.x) >> 6;
    int lane = threadIdx.x & 63;
    for (int n = gw; n < N; n += nw) {
        int r0 = rowptr[n], r1 = rowptr[n + 1];
        float di = dinv[n];
        u32 h = *(const u32*)(Hb + (size_t)n * 128 + lane * 2);
        float c = di * di;
        float a0 = bf16_lo(h) * c, a1 = bf16_hi(h) * c;

        for (int base = r0; base < r1; base += 64) {
            int cnt = min(64, r1 - base);
            int   myc = (lane < cnt) ? col[base + lane] : 0;
            float mdv = (lane < cnt) ? dinv[myc] : 0.0f;
            int e = 0;
            for (; e + 7 < cnt; e += 8) {
                u32 hh[8]; float cf[8];
#pragma unroll
                for (int j = 0; j < 8; j++) {
                    int   s = __shfl(myc, e + j);
                    cf[j]   = __shfl(mdv, e + j) * di;
                    hh[j]   = *(const u32*)(Hb + (size_t)s * 128 + lane * 2);
                }
#pragma unroll
                for (int j = 0; j < 8; j++) {
                    a0 += bf16_lo(hh[j]) * cf[j];
                    a1 += bf16_hi(hh[j]) * cf[j];
                }
            }
            for (; e + 3 < cnt; e += 4) {
                u32 hh[4]; float cf[4];
#pragma unroll
                for (int j = 0; j < 4; j++) {
                    int   s = __shfl(myc, e + j);
                    cf[j]   = __shfl(mdv, e + j) * di;
                    hh[j]   = *(const u32*)(Hb + (size_t)s * 128 + lane * 2);
                }
#pragma unroll
                for (int j = 0; j < 4; j++) {
                    a0 += bf16_lo(hh[j]) * cf[j];
                    a1 += bf16_hi(hh[j]) * cf[j];
                }
            }
            for (; e < cnt; e++) {
                int   s  = __shfl(myc, e);
                float cf = __shfl(mdv, e) * di;
                u32  hh  = *(const u32*)(Hb + (size_t)s * 128 + lane * 2);
                a0 += bf16_lo(hh) * cf; a1 += bf16_hi(hh) * cf;
            }
        }

        if (MODE == 0) {
            float r0f = fmaxf(a0, 0.0f), r1f = fmaxf(a1, 0.0f);
            ((u32*)outp)[(size_t)n * 64 + lane] = (u32)f2bf(r0f) | ((u32)f2bf(r1f) << 16);
        } else if (isbf) {
            ((u32*)outp)[(size_t)n * 64 + lane] = (u32)f2bf(a0) | ((u32)f2bf(a1) << 16);
        } else {
            ((float2*)outp)[(size_t)n * 64 + lane] = make_float2(a0, a1);
        }
    }
}

extern "C" void kernel_launch(void* const* d_in, const int* in_sizes, int n_in,
                              void* d_out, int out_size, void* d_ws, size_t ws_size,
                              hipStream_t stream) {
    const void* x  = d_in[0];
    const int*  ei = (const int*)d_in[1];
    const void* W1 = d_in[2];
    const void* W2 = d_in[3];

    const int N = in_sizes[0] / 128;   // 100000
    const int E = in_sizes[1] / 2;     // 1600000

    char* ws = (char*)d_ws;
    float* dinv    = (float*)ws;                         // 400KB
    int*   cnt     = (int*)(ws + (512u << 10));          // 400KB
    int*   rowptr  = (int*)(ws + (1024u << 10));         // 400KB+4
    int*   partial = (int*)(ws + (1536u << 10));         // ~512B
    int*   gbcnt   = (int*)(ws + (1600u << 10));         // (MAXNB+1)*4
    int*   gboff   = (int*)(ws + (1664u << 10));         // (MAXNB+1)*4
    int*   gbcur   = (int*)(ws + (1728u << 10));         // (MAXNB+1)*4
    int*   flag    = (int*)(ws + (1984u << 10));         // 4B
    u16*   W1t     = (u16*)(ws + (2048u << 10));         // 32KB
    u16*   W2t     = W1t + 128 * 128;                    // 32KB
    int*   col     = (int*)(ws + (3u << 20));            // E*4 = 6.4MB
    u16*   Hb      = (u16*)(ws + (10u << 20));           // N*256B = 25.6MB
    u16*   A       = (u16*)(ws + (40u << 20));           // N*256B = 25.6MB (bf16, relu'd)
    int2*  pairs   = (int2*)(ws + (70u << 20));          // 12.8MB (dead after k_fine)

    int P   = (N + 1023) / 1024;        // 98 scan blocks
    int NB  = (N + NPB - 1) / NPB;      // 391 buckets
    int nch = (E + CH - 1) / CH;        // 391 coarse chunks

    // ---- graph preprocessing (CSR by dst, bucketed build) ----
    k_detect<<<1, 256, 0, stream>>>((const u32*)x, flag);
    hipMemsetAsync(gbcnt, 0, (size_t)(MAXNB + 1) * 4, stream);
    k_bhist<<<nch, 256, 0, stream>>>(ei + E, gbcnt, E);
    k_bscan<<<1, 64, 0, stream>>>(gbcnt, gboff, gbcur, NB);
    k_coarse<<<nch, 256, 0, stream>>>(ei, gbcur, pairs, E);
    k_nodecnt<<<NB, 256, 0, stream>>>(pairs, gboff, cnt, N);
    k_dinv<<<(N + 255) / 256, 256, 0, stream>>>(cnt, dinv, N);
    k_blocksum<<<P, 256, 0, stream>>>(cnt, partial, N);
    k_scanpart<<<1, 64, 0, stream>>>(partial, rowptr + N, P);
    k_scanfinal<<<P, 1024, 0, stream>>>(cnt, partial, rowptr, cnt /*cursor*/, N);
    k_fine<<<NB, 256, 0, stream>>>(pairs, gboff, rowptr, col, N);
    k_transpose<<<128, 256, 0, stream>>>(W1, W2, W1t, W2t, flag);

    int ntiles  = N / 32;                 // 3125 (N divisible by 32)
    int gblocks = (ntiles + 3) / 4;       // 782 blocks, 1 tile per wave
    int ablocks = (N + 3) / 4;            // one wave per node

    // layer 1
    k_gemm<0><<<gblocks, 256, 0, stream>>>(x, W1t, Hb, ntiles, flag);
    k_csr_agg<0><<<ablocks, 256, 0, stream>>>(Hb, col, rowptr, dinv, A, N, flag);

    // layer 2 (relu fused into agg1 output; final dtype fused into agg2)
    k_gemm<1><<<gblocks, 256, 0, stream>>>(A, W2t, Hb, ntiles, flag);
    k_csr_agg<1><<<ablocks, 256, 0, stream>>>(Hb, col, rowptr, dinv, d_out, N, flag);
}

// Round 5
// 327.498 us; speedup vs baseline: 1.6868x; 1.0521x over previous
//
#include <hip/hip_runtime.h>
#include <hip/hip_bf16.h>

typedef unsigned short u16;
typedef unsigned int   u32;

typedef __attribute__((ext_vector_type(8))) short short8;
typedef __attribute__((ext_vector_type(4))) float floatx4;

#define HD __device__ __forceinline__

HD float bf16_lo(u32 u) { union { u32 i; float f; } v; v.i = u << 16; return v.f; }
HD float bf16_hi(u32 u) { union { u32 i; float f; } v; v.i = u & 0xffff0000u; return v.f; }
HD u16 f2bf(float f) {
    __hip_bfloat16 h = __float2bfloat16(f);
    u16 s; __builtin_memcpy(&s, &h, 2); return s;
}

// CSR bucketing parameters: 256 nodes per bucket (bucket = dst >> 8)
#define NPB   256
#define MAXNB 512          // supports N <= 131072
#define CH    4096         // edges per coarse chunk

// ---- fused: dtype detect + gbcnt zero + weight transpose ----
// Every block runs the cheap 16KB detect scan for its own isbf; block 0
// additionally publishes the flag and zeroes the bucket counters.
__global__ void k_wprep(const u32* __restrict__ xw,
                        const void* __restrict__ W1, const void* __restrict__ W2,
                        u16* __restrict__ W1t, u16* __restrict__ W2t,
                        int* __restrict__ flag, int* __restrict__ gbcnt) {
    __shared__ int cnt;
    if (threadIdx.x == 0) cnt = 0;
    __syncthreads();
    int sane = 0;
    for (int i = threadIdx.x; i < 4096; i += 256) {
        u32 v = xw[i];
        int e = (v >> 7) & 0xFF;
        sane += (e >= 107 && e <= 147) ? 1 : 0;
    }
    atomicAdd(&cnt, sane);
    __syncthreads();
    int isbf = (cnt > 2048) ? 1 : 0;
    if (blockIdx.x == 0) {
        if (threadIdx.x == 0) *flag = isbf;
        for (int i = threadIdx.x; i <= MAXNB; i += 256) gbcnt[i] = 0;
    }
    int i = blockIdx.x * blockDim.x + threadIdx.x;   // 0 .. 32767
    int w = i >> 14;
    int r = (i >> 7) & 127;
    int c = i & 127;
    const void* W = w ? W2 : W1;
    u16*       Wt = w ? W2t : W1t;
    u16 val;
    if (isbf) val = ((const u16*)W)[c * 128 + r];
    else      val = f2bf(((const float*)W)[c * 128 + r]);
    Wt[r * 128 + c] = val;
}

// ---- bucket histogram: LDS per-block then one global atomic per bucket ----
__global__ void k_bhist(const int* __restrict__ dst, int* __restrict__ gbcnt, int E) {
    __shared__ int h[MAXNB];
    for (int i = threadIdx.x; i < MAXNB; i += 256) h[i] = 0;
    __syncthreads();
    int base = blockIdx.x * CH;
    int end  = min(base + CH, E);
    for (int i = base + threadIdx.x; i < end; i += 256)
        atomicAdd(&h[dst[i] >> 8], 1);
    __syncthreads();
    for (int i = threadIdx.x; i < MAXNB; i += 256)
        if (h[i]) atomicAdd(&gbcnt[i], h[i]);
}

// ---- single-wave exclusive scan of bucket counts -> gboff, gbcursor ----
__global__ void k_bscan(const int* __restrict__ gbcnt, int* __restrict__ gboff,
                        int* __restrict__ gbcursor, int NB) {
    int lane = threadIdx.x;
    int carry = 0;
    int T = (NB + 63) / 64;
    for (int t = 0; t < T; t++) {
        int i = t * 64 + lane;
        int v = (i < NB) ? gbcnt[i] : 0;
        int x = v;
#pragma unroll
        for (int off = 1; off < 64; off <<= 1) {
            int y = __shfl_up(x, off);
            if (lane >= off) x += y;
        }
        if (i < NB) { int ex = carry + x - v; gboff[i] = ex; gbcursor[i] = ex; }
        carry += __shfl(x, 63);
    }
    if (lane == 0) gboff[NB] = carry;
}

// ---- coarse scatter: chunk -> LDS reorder by bucket -> contiguous run copy ----
__global__ void __launch_bounds__(256)
k_coarse(const int* __restrict__ ei, int* __restrict__ gbcursor,
         int2* __restrict__ pairs, int E) {
    __shared__ int  hist[MAXNB];
    __shared__ int  gs[MAXNB];
    __shared__ int  dlt[MAXNB];
    __shared__ int  lofs[MAXNB];
    __shared__ int2 lp[CH];
    __shared__ u16  pb[CH];
    const int* srcp = ei;
    const int* dstp = ei + E;
    int base = blockIdx.x * CH;
    int cnt  = min(CH, E - base);

    for (int i = threadIdx.x; i < MAXNB; i += 256) hist[i] = 0;
    __syncthreads();

    int2 e[16];
    int nb_ = 0;
#pragma unroll
    for (int j = 0; j < 16; j++) {
        int i = base + threadIdx.x + j * 256;
        if (i < E) {
            e[j].x = srcp[i];
            e[j].y = dstp[i];
            atomicAdd(&hist[e[j].y >> 8], 1);
            nb_ = j + 1;
        }
    }
    __syncthreads();

    // wave0: exclusive scan of hist into gs
    if (threadIdx.x < 64) {
        int lane = threadIdx.x;
        int carry = 0;
#pragma unroll
        for (int t = 0; t < MAXNB / 64; t++) {
            int i = t * 64 + lane;
            int v = hist[i];
            int x = v;
#pragma unroll
            for (int off = 1; off < 64; off <<= 1) {
                int y = __shfl_up(x, off);
                if (lane >= off) x += y;
            }
            gs[i] = carry + x - v;
            carry += __shfl(x, 63);
        }
    }
    __syncthreads();

    // reserve global space per bucket (one atomic per non-empty bucket)
    for (int b = threadIdx.x; b < MAXNB; b += 256) {
        int c = hist[b];
        lofs[b] = gs[b];
        if (c > 0) {
            int gbase = atomicAdd(&gbcursor[b], c);
            dlt[b] = gbase - gs[b];
        }
    }
    __syncthreads();

    // scatter into LDS grouped by bucket
    for (int j = 0; j < nb_; j++) {
        int b = e[j].y >> 8;
        int p = atomicAdd(&lofs[b], 1);
        lp[p] = e[j];
        pb[p] = (u16)b;
    }
    __syncthreads();

    // contiguous-run copy to global
    for (int p = threadIdx.x; p < cnt; p += 256) {
        pairs[p + dlt[pb[p]]] = lp[p];
    }
}

// ---- fused per-bucket CSR finalize: counts + dinv + in-LDS scan -> rowptr,
// then cursor-scatter col. rowptr[n] = gboff[b] + local prefix (bucket-major
// col layout makes the global hierarchical scan unnecessary).
__global__ void __launch_bounds__(256)
k_bucket(const int2* __restrict__ pairs, const int* __restrict__ gboff,
         float* __restrict__ dinv, int* __restrict__ rowptr,
         int* __restrict__ col, int N, int E) {
    __shared__ int lc[NPB];
    __shared__ int lcur[NPB];
    __shared__ int ws[4];
    __shared__ int wsoff[4];
    int b = blockIdx.x;
    int nbase = b * NPB;
    int tid = threadIdx.x, lane = tid & 63, wid = tid >> 6;
    lc[tid] = 0;
    __syncthreads();
    int p0 = gboff[b], p1 = gboff[b + 1];
    for (int p = p0 + tid; p < p1; p += 256)
        atomicAdd(&lc[pairs[p].y - nbase], 1);
    __syncthreads();
    int v = lc[tid];
    int node = nbase + tid;
    if (node < N) dinv[node] = rsqrtf((float)v + 1.0f);
    // 256-wide exclusive scan: wave-level inclusive + tiny cross-wave prefix
    int x = v;
#pragma unroll
    for (int off = 1; off < 64; off <<= 1) {
        int y = __shfl_up(x, off);
        if (lane >= off) x += y;
    }
    if (lane == 63) ws[wid] = x;
    __syncthreads();
    if (tid == 0) {
        int s = 0;
#pragma unroll
        for (int k2 = 0; k2 < 4; k2++) { wsoff[k2] = s; s += ws[k2]; }
    }
    __syncthreads();
    int excl = p0 + wsoff[wid] + (x - v);
    if (node < N) rowptr[node] = excl;
    lcur[tid] = excl;
    if (b == 0 && tid == 0) rowptr[N] = E;
    __syncthreads();
    for (int p = p0 + tid; p < p1; p += 256) {
        int2 e = pairs[p];
        int pos = atomicAdd(&lcur[e.y - nbase], 1);
        col[pos] = e.x;
    }
}

// ---- GEMM: out[r][c] = sum_k in[r][k] * W[k][c], K=C=128, bf16 out ----
// Weights staged to LDS once per block (XOR-swizzled 16B slots). Each wave
// computes a 32x128 tile (2 row-groups sharing each B frag).
// MODE 0: input x (dtype per flag). MODE 1: input bf16 (A, relu pre-applied).
template <int MODE>
__global__ void __launch_bounds__(256)
k_gemm(const void* __restrict__ inp, const u16* __restrict__ Wt,
       u16* __restrict__ outb, int ntiles, const int* __restrict__ flagp) {
    __shared__ u16 lw[128 * 128];        // weights [c][k], swizzled slots
    __shared__ u16 stage[4][16 * 136];   // per-wave C staging
    int isbf = (MODE == 0) ? *flagp : 1;
    int gw   = (blockIdx.x * blockDim.x + threadIdx.x) >> 6;
    int nw   = (gridDim.x * blockDim.x) >> 6;
    int lane = threadIdx.x & 63;
    int wid  = threadIdx.x >> 6;
    int m = lane & 15, q = lane >> 4;
    u16* st = stage[wid];

    // stage weights: 256 threads, each covers half a row (8 x 16B slots)
    {
        int r = threadIdx.x >> 1;
        int h = threadIdx.x & 1;
        const short8* src = (const short8*)(Wt + r * 128 + h * 64);
#pragma unroll
        for (int jj = 0; jj < 8; jj++) {
            int slot = h * 8 + jj;
            *(short8*)&lw[r * 128 + ((slot ^ (r & 7)) << 3)] = src[jj];
        }
    }
    __syncthreads();

    for (int t = gw; t < ntiles; t += nw) {
        long r0 = (long)t * 32;
        floatx4 acc[2][8];
#pragma unroll
        for (int g = 0; g < 2; g++)
#pragma unroll
            for (int nt = 0; nt < 8; nt++) acc[g][nt] = (floatx4)0.0f;

        // hoisted A loads: 8 independent 16B fetches
        short8 a[2][4];
        if (MODE == 1 || isbf) {
#pragma unroll
            for (int g = 0; g < 2; g++)
#pragma unroll
                for (int kk = 0; kk < 4; kk++)
                    a[g][kk] = *(const short8*)((const u16*)inp +
                                 (r0 + g * 16 + m) * 128 + kk * 32 + q * 8);
        } else {
#pragma unroll
            for (int g = 0; g < 2; g++)
#pragma unroll
                for (int kk = 0; kk < 4; kk++) {
                    const float4* fp = (const float4*)((const float*)inp +
                                 (r0 + g * 16 + m) * 128 + kk * 32 + q * 8);
                    float4 f0 = fp[0], f1 = fp[1];
                    short8 v;
                    v[0] = (short)f2bf(f0.x); v[1] = (short)f2bf(f0.y);
                    v[2] = (short)f2bf(f0.z); v[3] = (short)f2bf(f0.w);
                    v[4] = (short)f2bf(f1.x); v[5] = (short)f2bf(f1.y);
                    v[6] = (short)f2bf(f1.z); v[7] = (short)f2bf(f1.w);
                    a[g][kk] = v;
                }
        }

#pragma unroll
        for (int kk = 0; kk < 4; kk++) {
#pragma unroll
            for (int nt = 0; nt < 8; nt++) {
                int slot = kk * 4 + q;
                short8 b = *(const short8*)&lw[(nt * 16 + m) * 128 +
                                               ((slot ^ (m & 7)) << 3)];
                acc[0][nt] = __builtin_amdgcn_mfma_f32_16x16x32_bf16(a[0][kk], b, acc[0][nt], 0, 0, 0);
                acc[1][nt] = __builtin_amdgcn_mfma_f32_16x16x32_bf16(a[1][kk], b, acc[1][nt], 0, 0, 0);
            }
        }

        // epilogue: stage each 16x128 row-group in LDS, coalesced store
#pragma unroll
        for (int g = 0; g < 2; g++) {
#pragma unroll
            for (int nt = 0; nt < 8; nt++)
#pragma unroll
                for (int i = 0; i < 4; i++)
                    st[(q * 4 + i) * 136 + nt * 16 + m] = f2bf(acc[g][nt][i]);
            __builtin_amdgcn_s_waitcnt(0);   // drain ds_write before read
            u16* gbase = outb + (size_t)(r0 + g * 16) * 128;
#pragma unroll
            for (int j = 0; j < 4; j++) {
                int e   = lane * 8 + j * 512;
                int row = e >> 7, colu = e & 127;
                short8 vv = *(const short8*)&st[row * 136 + colu];
                *(short8*)(gbase + e) = vv;
            }
            __builtin_amdgcn_s_waitcnt(0);   // reads done before g=1 rewrites
        }
    }
}

// ---- CSR aggregation: one wave per node, 16-deep batched-gather pipeline ----
// MODE 0: write bf16 with fused relu (intermediate A).
// MODE 1: final output (bf16 or fp32 per flag).
template <int MODE>
__global__ void k_csr_agg(const u16* __restrict__ Hb, const int* __restrict__ col,
                          const int* __restrict__ rowptr, const float* __restrict__ dinv,
                          void* __restrict__ outp, int N, const int* __restrict__ flagp) {
    int isbf = MODE ? *flagp : 1;
    int gw   = (blockIdx.x * blockDim.x + threadIdx.x) >> 6;
    int nw   = (gridDim.x * blockDim.x) >> 6;
    int lane = threadIdx.x & 63;
    for (int n = gw; n < N; n += nw) {
        int r0 = rowptr[n], r1 = rowptr[n + 1];
        float di = dinv[n];
        u32 h = *(const u32*)(Hb + (size_t)n * 128 + lane * 2);
        float c = di * di;
        float a0 = bf16_lo(h) * c, a1 = bf16_hi(h) * c;

        for (int base = r0; base < r1; base += 64) {
            int cnt = min(64, r1 - base);
            int   myc = (lane < cnt) ? col[base + lane] : 0;
            float mdv = (lane < cnt) ? dinv[myc] : 0.0f;
            int e = 0;
            for (; e + 15 < cnt; e += 16) {
                u32 hh[16]; float cf[16];
#pragma unroll
                for (int j = 0; j < 16; j++) {
                    int   s = __shfl(myc, e + j);
                    cf[j]   = __shfl(mdv, e + j) * di;
                    hh[j]   = *(const u32*)(Hb + (size_t)s * 128 + lane * 2);
                }
#pragma unroll
                for (int j = 0; j < 16; j++) {
                    a0 += bf16_lo(hh[j]) * cf[j];
                    a1 += bf16_hi(hh[j]) * cf[j];
                }
            }
            for (; e + 7 < cnt; e += 8) {
                u32 hh[8]; float cf[8];
#pragma unroll
                for (int j = 0; j < 8; j++) {
                    int   s = __shfl(myc, e + j);
                    cf[j]   = __shfl(mdv, e + j) * di;
                    hh[j]   = *(const u32*)(Hb + (size_t)s * 128 + lane * 2);
                }
#pragma unroll
                for (int j = 0; j < 8; j++) {
                    a0 += bf16_lo(hh[j]) * cf[j];
                    a1 += bf16_hi(hh[j]) * cf[j];
                }
            }
            for (; e + 3 < cnt; e += 4) {
                u32 hh[4]; float cf[4];
#pragma unroll
                for (int j = 0; j < 4; j++) {
                    int   s = __shfl(myc, e + j);
                    cf[j]   = __shfl(mdv, e + j) * di;
                    hh[j]   = *(const u32*)(Hb + (size_t)s * 128 + lane * 2);
                }
#pragma unroll
                for (int j = 0; j < 4; j++) {
                    a0 += bf16_lo(hh[j]) * cf[j];
                    a1 += bf16_hi(hh[j]) * cf[j];
                }
            }
            for (; e < cnt; e++) {
                int   s  = __shfl(myc, e);
                float cf = __shfl(mdv, e) * di;
                u32  hh  = *(const u32*)(Hb + (size_t)s * 128 + lane * 2);
                a0 += bf16_lo(hh) * cf; a1 += bf16_hi(hh) * cf;
            }
        }

        if (MODE == 0) {
            float r0f = fmaxf(a0, 0.0f), r1f = fmaxf(a1, 0.0f);
            ((u32*)outp)[(size_t)n * 64 + lane] = (u32)f2bf(r0f) | ((u32)f2bf(r1f) << 16);
        } else if (isbf) {
            ((u32*)outp)[(size_t)n * 64 + lane] = (u32)f2bf(a0) | ((u32)f2bf(a1) << 16);
        } else {
            ((float2*)outp)[(size_t)n * 64 + lane] = make_float2(a0, a1);
        }
    }
}

extern "C" void kernel_launch(void* const* d_in, const int* in_sizes, int n_in,
                              void* d_out, int out_size, void* d_ws, size_t ws_size,
                              hipStream_t stream) {
    const void* x  = d_in[0];
    const int*  ei = (const int*)d_in[1];
    const void* W1 = d_in[2];
    const void* W2 = d_in[3];

    const int N = in_sizes[0] / 128;   // 100000
    const int E = in_sizes[1] / 2;     // 1600000

    char* ws = (char*)d_ws;
    float* dinv    = (float*)ws;                         // 400KB
    int*   rowptr  = (int*)(ws + (1024u << 10));         // 400KB+4
    int*   gbcnt   = (int*)(ws + (1600u << 10));         // (MAXNB+1)*4
    int*   gboff   = (int*)(ws + (1664u << 10));         // (MAXNB+1)*4
    int*   gbcur   = (int*)(ws + (1728u << 10));         // (MAXNB+1)*4
    int*   flag    = (int*)(ws + (1984u << 10));         // 4B
    u16*   W1t     = (u16*)(ws + (2048u << 10));         // 32KB
    u16*   W2t     = W1t + 128 * 128;                    // 32KB
    int*   col     = (int*)(ws + (3u << 20));            // E*4 = 6.4MB
    u16*   Hb      = (u16*)(ws + (10u << 20));           // N*256B = 25.6MB
    u16*   A       = (u16*)(ws + (40u << 20));           // N*256B = 25.6MB (bf16, relu'd)
    int2*  pairs   = (int2*)(ws + (70u << 20));          // 12.8MB (dead after k_bucket)

    int NB  = (N + NPB - 1) / NPB;      // 391 buckets
    int nch = (E + CH - 1) / CH;        // 391 coarse chunks

    // ---- graph preprocessing (CSR by dst, bucketed build) ----
    k_wprep<<<128, 256, 0, stream>>>((const u32*)x, W1, W2, W1t, W2t, flag, gbcnt);
    k_bhist<<<nch, 256, 0, stream>>>(ei + E, gbcnt, E);
    k_bscan<<<1, 64, 0, stream>>>(gbcnt, gboff, gbcur, NB);
    k_coarse<<<nch, 256, 0, stream>>>(ei, gbcur, pairs, E);
    k_bucket<<<NB, 256, 0, stream>>>(pairs, gboff, dinv, rowptr, col, N, E);

    int ntiles  = N / 32;                 // 3125 (N divisible by 32)
    int gblocks = (ntiles + 3) / 4;       // 782 blocks, 1 tile per wave
    int ablocks = (N + 3) / 4;            // one wave per node

    // layer 1
    k_gemm<0><<<gblocks, 256, 0, stream>>>(x, W1t, Hb, ntiles, flag);
    k_csr_agg<0><<<ablocks, 256, 0, stream>>>(Hb, col, rowptr, dinv, A, N, flag);

    // layer 2 (relu fused into agg1 output; final dtype fused into agg2)
    k_gemm<1><<<gblocks, 256, 0, stream>>>(A, W2t, Hb, ntiles, flag);
    k_csr_agg<1><<<ablocks, 256, 0, stream>>>(Hb, col, rowptr, dinv, d_out, N, flag);
}